// Round 1
// baseline (566.958 us; speedup 1.0000x reference)
//
#include <hip/hip_runtime.h>

typedef unsigned short u16;
typedef unsigned int u32;
typedef short bf16x8 __attribute__((ext_vector_type(8)));
typedef float f32x4 __attribute__((ext_vector_type(4)));

#define S_LEN 4096
#define DM 1024
#define NH 16
#define DH 64
#define ATT_SCALE 0.125f

typedef const __attribute__((address_space(1))) u32 gu32;
typedef __attribute__((address_space(3))) u32 lu32;

__device__ __forceinline__ u16 f2bf(float f) {
  u32 u = __builtin_bit_cast(u32, f);
  u += 0x7fff + ((u >> 16) & 1);
  return (u16)(u >> 16);
}

// ---------------- fp32 -> bf16 conversion (vectorized x4) ----------------
__global__ void cvt_bf16(const float* __restrict__ in, u16* __restrict__ out, int n4) {
  int i = blockIdx.x * blockDim.x + threadIdx.x;
  if (i < n4) {
    float4 v = ((const float4*)in)[i];
    ushort4 o;
    o.x = f2bf(v.x); o.y = f2bf(v.y); o.z = f2bf(v.z); o.w = f2bf(v.w);
    ((ushort4*)out)[i] = o;
  }
}

// ---------------- GEMM: C[M,N] = A[M,K] * Bt[N,K]^T + bias ----------------
// MODE 0: C bf16 row-major [M][N]
// MODE 1: C bf16 transposed [N][M]   (used to produce V^T for attention)
// MODE 2: C fp32 row-major [M][N]    (final output)
template<int MODE>
__global__ __launch_bounds__(256) void gemm128(const u16* __restrict__ A,
                                               const u16* __restrict__ Bt,
                                               const float* __restrict__ bias,
                                               void* __restrict__ Cp,
                                               int M, int N, int K) {
  __shared__ __align__(16) u16 As[128 * 32];
  __shared__ __align__(16) u16 Bs[128 * 32];
  const int tid = threadIdx.x;
  const int lane = tid & 63;
  const int wid = tid >> 6;
  const int wm = wid >> 1, wn = wid & 1;          // 2x2 waves, each 64x64 out
  const int bm = blockIdx.x * 128, bn = blockIdx.y * 128;
  const int lr = lane & 15, lg = lane >> 4;

  f32x4 acc[4][4];
#pragma unroll
  for (int i = 0; i < 4; ++i)
#pragma unroll
    for (int j = 0; j < 4; ++j) acc[i][j] = f32x4{0.f, 0.f, 0.f, 0.f};

  const int r0 = tid >> 2;
  const int c0 = (tid & 3) * 8;
  const u16* ga0 = A + (size_t)(bm + r0) * K + c0;
  const u16* gb0 = Bt + (size_t)(bn + r0) * K + c0;

  for (int kt = 0; kt < K; kt += 32) {
    __builtin_amdgcn_global_load_lds((gu32*)(ga0 + kt),            (lu32*)(As + tid * 8),        16, 0, 0);
    __builtin_amdgcn_global_load_lds((gu32*)(ga0 + 64 * K + kt),   (lu32*)(As + 2048 + tid * 8), 16, 0, 0);
    __builtin_amdgcn_global_load_lds((gu32*)(gb0 + kt),            (lu32*)(Bs + tid * 8),        16, 0, 0);
    __builtin_amdgcn_global_load_lds((gu32*)(gb0 + 64 * K + kt),   (lu32*)(Bs + 2048 + tid * 8), 16, 0, 0);
    __syncthreads();
    bf16x8 af[4], bfr[4];
#pragma unroll
    for (int i = 0; i < 4; ++i) af[i] = *(const bf16x8*)&As[(wm * 64 + i * 16 + lr) * 32 + lg * 8];
#pragma unroll
    for (int j = 0; j < 4; ++j) bfr[j] = *(const bf16x8*)&Bs[(wn * 64 + j * 16 + lr) * 32 + lg * 8];
#pragma unroll
    for (int i = 0; i < 4; ++i)
#pragma unroll
      for (int j = 0; j < 4; ++j)
        acc[i][j] = __builtin_amdgcn_mfma_f32_16x16x32_bf16(af[i], bfr[j], acc[i][j], 0, 0, 0);
    __syncthreads();
  }

#pragma unroll
  for (int i = 0; i < 4; ++i) {
    const int row = bm + wm * 64 + i * 16 + lg * 4;
#pragma unroll
    for (int j = 0; j < 4; ++j) {
      const int col = bn + wn * 64 + j * 16 + lr;
      const float b = bias[col];
#pragma unroll
      for (int r = 0; r < 4; ++r) {
        const float v = acc[i][j][r] + b;
        if (MODE == 0)      ((u16*)Cp)[(size_t)(row + r) * N + col] = f2bf(v);
        else if (MODE == 1) ((u16*)Cp)[(size_t)col * M + (row + r)] = f2bf(v);
        else                ((float*)Cp)[(size_t)(row + r) * N + col] = v;
      }
    }
  }
}

// ---------------- causal flash attention ----------------
// 1 wave / block, 16 q-rows / wave, KV tiles of 32.
// Q,K stored [s][1024] bf16 ; V stored transposed [1024][4096] bf16 (VT).
// O written [s][1024] bf16.
__global__ __launch_bounds__(64) void attn_fwd(const u16* __restrict__ Q,
                                               const u16* __restrict__ K,
                                               const u16* __restrict__ VT,
                                               u16* __restrict__ O) {
  __shared__ __align__(16) u16 P[16 * 40];   // stride 40 elems = 80B: 2-way bank alias only
  const int lane = threadIdx.x;
  const int lr = lane & 15, lg = lane >> 4;
  const int h = blockIdx.y;
  const int qb = blockIdx.x * 16;

  const size_t qoff = (size_t)(qb + lr) * DM + h * DH + lg * 8;
  const bf16x8 qa0 = *(const bf16x8*)&Q[qoff];
  const bf16x8 qa1 = *(const bf16x8*)&Q[qoff + 32];

  f32x4 o0 = {0.f,0.f,0.f,0.f}, o1 = {0.f,0.f,0.f,0.f}, o2 = {0.f,0.f,0.f,0.f}, o3 = {0.f,0.f,0.f,0.f};
  float m[4], lsum[4];
#pragma unroll
  for (int r = 0; r < 4; ++r) { m[r] = -1e30f; lsum[r] = 0.f; }

  const int ntile = (qb + 16 + 31) >> 5;   // keys 0 .. qb+15 needed
  for (int kt = 0; kt < ntile; ++kt) {
    const int tb = kt * 32;
    const size_t koff = (size_t)(tb + lr) * DM + h * DH + lg * 8;
    const bf16x8 k00 = *(const bf16x8*)&K[koff];
    const bf16x8 k01 = *(const bf16x8*)&K[koff + 32];
    const bf16x8 k10 = *(const bf16x8*)&K[koff + (size_t)16 * DM];
    const bf16x8 k11 = *(const bf16x8*)&K[koff + (size_t)16 * DM + 32];
    f32x4 s0 = {0.f,0.f,0.f,0.f}, s1 = {0.f,0.f,0.f,0.f};
    s0 = __builtin_amdgcn_mfma_f32_16x16x32_bf16(qa0, k00, s0, 0, 0, 0);
    s0 = __builtin_amdgcn_mfma_f32_16x16x32_bf16(qa1, k01, s0, 0, 0, 0);
    s1 = __builtin_amdgcn_mfma_f32_16x16x32_bf16(qa0, k10, s1, 0, 0, 0);
    s1 = __builtin_amdgcn_mfma_f32_16x16x32_bf16(qa1, k11, s1, 0, 0, 0);

#pragma unroll
    for (int r = 0; r < 4; ++r) {
      const int qg = qb + lg * 4 + r;
      float v0 = (tb + lr <= qg)      ? s0[r] * ATT_SCALE : -1e30f;
      float v1 = (tb + 16 + lr <= qg) ? s1[r] * ATT_SCALE : -1e30f;
      float mx = fmaxf(v0, v1);
      mx = fmaxf(mx, __shfl_xor(mx, 1));
      mx = fmaxf(mx, __shfl_xor(mx, 2));
      mx = fmaxf(mx, __shfl_xor(mx, 4));
      mx = fmaxf(mx, __shfl_xor(mx, 8));
      const float mn = fmaxf(m[r], mx);
      const float al = __expf(m[r] - mn);
      const float p0 = __expf(v0 - mn);
      const float p1 = __expf(v1 - mn);
      float rs = p0 + p1;
      rs += __shfl_xor(rs, 1);
      rs += __shfl_xor(rs, 2);
      rs += __shfl_xor(rs, 4);
      rs += __shfl_xor(rs, 8);
      lsum[r] = lsum[r] * al + rs;
      m[r] = mn;
      o0[r] *= al; o1[r] *= al; o2[r] *= al; o3[r] *= al;
      const int prow = lg * 4 + r;
      P[prow * 40 + lr]      = f2bf(p0);
      P[prow * 40 + 16 + lr] = f2bf(p1);
    }
    __syncthreads();
    const bf16x8 pa = *(const bf16x8*)&P[lr * 40 + lg * 8];
    const u16* vb = VT + (size_t)(h * DH + lr) * S_LEN + tb + lg * 8;
    const bf16x8 v0f = *(const bf16x8*)&vb[0];
    const bf16x8 v1f = *(const bf16x8*)&vb[(size_t)16 * S_LEN];
    const bf16x8 v2f = *(const bf16x8*)&vb[(size_t)32 * S_LEN];
    const bf16x8 v3f = *(const bf16x8*)&vb[(size_t)48 * S_LEN];
    o0 = __builtin_amdgcn_mfma_f32_16x16x32_bf16(pa, v0f, o0, 0, 0, 0);
    o1 = __builtin_amdgcn_mfma_f32_16x16x32_bf16(pa, v1f, o1, 0, 0, 0);
    o2 = __builtin_amdgcn_mfma_f32_16x16x32_bf16(pa, v2f, o2, 0, 0, 0);
    o3 = __builtin_amdgcn_mfma_f32_16x16x32_bf16(pa, v3f, o3, 0, 0, 0);
    __syncthreads();
  }

#pragma unroll
  for (int r = 0; r < 4; ++r) {
    const float inv = 1.f / lsum[r];
    const size_t obase = (size_t)(qb + lg * 4 + r) * DM + h * DH;
    O[obase + 0 * 16 + lr] = f2bf(o0[r] * inv);
    O[obase + 1 * 16 + lr] = f2bf(o1[r] * inv);
    O[obase + 2 * 16 + lr] = f2bf(o2[r] * inv);
    O[obase + 3 * 16 + lr] = f2bf(o3[r] * inv);
  }
}

// ---------------- host launch ----------------
extern "C" void kernel_launch(void* const* d_in, const int* in_sizes, int n_in,
                              void* d_out, int out_size, void* d_ws, size_t ws_size,
                              hipStream_t stream) {
  const float* x  = (const float*)d_in[0];
  const float* Wq = (const float*)d_in[1];
  const float* bq = (const float*)d_in[2];
  const float* Wk = (const float*)d_in[3];
  const float* bk = (const float*)d_in[4];
  const float* Wv = (const float*)d_in[5];
  const float* bv = (const float*)d_in[6];
  const float* Wo = (const float*)d_in[7];
  const float* bo = (const float*)d_in[8];
  float* out = (float*)d_out;

  u16* xb  = (u16*)d_ws;                      // [4096][1024]
  u16* wqb = xb  + (size_t)S_LEN * DM;        // [1024][1024] each
  u16* wkb = wqb + (size_t)DM * DM;
  u16* wvb = wkb + (size_t)DM * DM;
  u16* wob = wvb + (size_t)DM * DM;
  u16* qbf = wob + (size_t)DM * DM;           // [4096][1024]
  u16* kbf = qbf + (size_t)S_LEN * DM;        // [4096][1024]
  u16* vtb = kbf + (size_t)S_LEN * DM;        // [1024][4096]  (V^T)
  u16* obf = vtb + (size_t)S_LEN * DM;        // [4096][1024]

  cvt_bf16<<<(S_LEN * DM / 4 + 255) / 256, 256, 0, stream>>>(x,  xb,  S_LEN * DM / 4);
  cvt_bf16<<<(DM * DM / 4 + 255) / 256, 256, 0, stream>>>(Wq, wqb, DM * DM / 4);
  cvt_bf16<<<(DM * DM / 4 + 255) / 256, 256, 0, stream>>>(Wk, wkb, DM * DM / 4);
  cvt_bf16<<<(DM * DM / 4 + 255) / 256, 256, 0, stream>>>(Wv, wvb, DM * DM / 4);
  cvt_bf16<<<(DM * DM / 4 + 255) / 256, 256, 0, stream>>>(Wo, wob, DM * DM / 4);

  dim3 gg(S_LEN / 128, DM / 128);
  gemm128<0><<<gg, 256, 0, stream>>>(xb, wqb, bq, qbf, S_LEN, DM, DM);
  gemm128<0><<<gg, 256, 0, stream>>>(xb, wkb, bk, kbf, S_LEN, DM, DM);
  gemm128<1><<<gg, 256, 0, stream>>>(xb, wvb, bv, vtb, S_LEN, DM, DM);

  attn_fwd<<<dim3(S_LEN / 16, NH), 64, 0, stream>>>(qbf, kbf, vtb, obf);

  gemm128<2><<<gg, 256, 0, stream>>>(obf, wob, bo, out, S_LEN, DM, DM);
}

// Round 2
// 280.813 us; speedup vs baseline: 2.0190x; 2.0190x over previous
//
#include <hip/hip_runtime.h>

typedef unsigned short u16;
typedef unsigned int u32;
typedef short bf16x8 __attribute__((ext_vector_type(8)));
typedef float f32x4 __attribute__((ext_vector_type(4)));
typedef float f32x16 __attribute__((ext_vector_type(16)));
typedef u32 u32x4 __attribute__((ext_vector_type(4)));

#define S_LEN 4096
#define DM 1024
#define NH 16
#define DH 64
#define CE 0.18033688f   // (1/sqrt(64)) * log2(e)

typedef const __attribute__((address_space(1))) u32 gu32;
typedef __attribute__((address_space(3))) u32 lu32;

__device__ __forceinline__ u16 f2bf(float f) {
  u32 u = __builtin_bit_cast(u32, f);
  u += 0x7fff + ((u >> 16) & 1);
  return (u16)(u >> 16);
}

__device__ __forceinline__ f32x16 zero16() {
  f32x16 z;
#pragma unroll
  for (int i = 0; i < 16; ++i) z[i] = 0.f;
  return z;
}

__device__ __forceinline__ u32 cvt_pk_bf16(float lo, float hi) {
  u32 r;
  asm("v_cvt_pk_bf16_f32 %0, %1, %2" : "=v"(r) : "v"(lo), "v"(hi));
  return r;
}

// ---------------- fp32 -> bf16 conversion (vectorized x4) ----------------
__global__ void cvt_bf16(const float* __restrict__ in, u16* __restrict__ out, int n4) {
  int i = blockIdx.x * blockDim.x + threadIdx.x;
  if (i < n4) {
    float4 v = ((const float4*)in)[i];
    ushort4 o;
    o.x = f2bf(v.x); o.y = f2bf(v.y); o.z = f2bf(v.z); o.w = f2bf(v.w);
    ((ushort4*)out)[i] = o;
  }
}

// ---------------- GEMM: C[M,N] = A[M,K] * Bt[N,K]^T + bias ----------------
// MODE 0: C bf16 row-major [M][N]
// MODE 1: C bf16 transposed [N][M]   (used to produce V^T for attention)
// MODE 2: C fp32 row-major [M][N]    (final output)
template<int MODE>
__global__ __launch_bounds__(256) void gemm128(const u16* __restrict__ A,
                                               const u16* __restrict__ Bt,
                                               const float* __restrict__ bias,
                                               void* __restrict__ Cp,
                                               int M, int N, int K) {
  __shared__ __align__(16) u16 As[128 * 32];
  __shared__ __align__(16) u16 Bs[128 * 32];
  const int tid = threadIdx.x;
  const int lane = tid & 63;
  const int wid = tid >> 6;
  const int wm = wid >> 1, wn = wid & 1;          // 2x2 waves, each 64x64 out
  const int bm = blockIdx.x * 128, bn = blockIdx.y * 128;
  const int lr = lane & 15, lg = lane >> 4;

  f32x4 acc[4][4];
#pragma unroll
  for (int i = 0; i < 4; ++i)
#pragma unroll
    for (int j = 0; j < 4; ++j) acc[i][j] = f32x4{0.f, 0.f, 0.f, 0.f};

  const int r0 = tid >> 2;
  const int c0 = (tid & 3) * 8;
  const u16* ga0 = A + (size_t)(bm + r0) * K + c0;
  const u16* gb0 = Bt + (size_t)(bn + r0) * K + c0;

  for (int kt = 0; kt < K; kt += 32) {
    __builtin_amdgcn_global_load_lds((gu32*)(ga0 + kt),            (lu32*)(As + tid * 8),        16, 0, 0);
    __builtin_amdgcn_global_load_lds((gu32*)(ga0 + 64 * K + kt),   (lu32*)(As + 2048 + tid * 8), 16, 0, 0);
    __builtin_amdgcn_global_load_lds((gu32*)(gb0 + kt),            (lu32*)(Bs + tid * 8),        16, 0, 0);
    __builtin_amdgcn_global_load_lds((gu32*)(gb0 + 64 * K + kt),   (lu32*)(Bs + 2048 + tid * 8), 16, 0, 0);
    __syncthreads();
    bf16x8 af[4], bfr[4];
#pragma unroll
    for (int i = 0; i < 4; ++i) af[i] = *(const bf16x8*)&As[(wm * 64 + i * 16 + lr) * 32 + lg * 8];
#pragma unroll
    for (int j = 0; j < 4; ++j) bfr[j] = *(const bf16x8*)&Bs[(wn * 64 + j * 16 + lr) * 32 + lg * 8];
#pragma unroll
    for (int i = 0; i < 4; ++i)
#pragma unroll
      for (int j = 0; j < 4; ++j)
        acc[i][j] = __builtin_amdgcn_mfma_f32_16x16x32_bf16(af[i], bfr[j], acc[i][j], 0, 0, 0);
    __syncthreads();
  }

#pragma unroll
  for (int i = 0; i < 4; ++i) {
    const int row = bm + wm * 64 + i * 16 + lg * 4;
#pragma unroll
    for (int j = 0; j < 4; ++j) {
      const int col = bn + wn * 64 + j * 16 + lr;
      const float b = bias[col];
#pragma unroll
      for (int r = 0; r < 4; ++r) {
        const float v = acc[i][j][r] + b;
        if (MODE == 0)      ((u16*)Cp)[(size_t)(row + r) * N + col] = f2bf(v);
        else if (MODE == 1) ((u16*)Cp)[(size_t)col * M + (row + r)] = f2bf(v);
        else                ((float*)Cp)[(size_t)(row + r) * N + col] = v;
      }
    }
  }
}

// ---------------- causal flash attention, 32x32 MFMA, swapped-QK ----------------
// Per wave: 32 q-rows. QK^T computed as mfma(K, Q) -> C[k][q] so each lane owns
// one q-row's scores (col = lane&31). PV computed as O^T = mfma(VT, P^T) -> C[d][q],
// keeping softmax state lane-local. No LDS, no barriers.
// k-coverage per lane (32x32x16 C-layout): k = (r&3) + 8*(r>>2) + 4*(lane>>5).

template<bool DIAG>
__device__ __forceinline__ void attn_tile(int kb, int h, int ll, int hi, int lld,
                                          const u16* __restrict__ K, const u16* __restrict__ VT,
                                          const bf16x8* qf, f32x16& o0, f32x16& o1,
                                          float& m, float& lsum) {
  const u16* krow = K + (size_t)(kb + ll) * DM + h * DH + hi * 8;
  f32x16 s = zero16();
  s = __builtin_amdgcn_mfma_f32_32x32x16_bf16(*(const bf16x8*)&krow[0],  qf[0], s, 0, 0, 0);
  s = __builtin_amdgcn_mfma_f32_32x32x16_bf16(*(const bf16x8*)&krow[16], qf[1], s, 0, 0, 0);
  s = __builtin_amdgcn_mfma_f32_32x32x16_bf16(*(const bf16x8*)&krow[32], qf[2], s, 0, 0, 0);
  s = __builtin_amdgcn_mfma_f32_32x32x16_bf16(*(const bf16x8*)&krow[48], qf[3], s, 0, 0, 0);

  float p[16];
#pragma unroll
  for (int r = 0; r < 16; ++r) {
    const int kl = (r & 3) + 8 * (r >> 2);      // + 4*hi handled via lld
    float v = s[r] * CE;
    if (DIAG) v = (kl <= lld) ? v : -1e30f;
    p[r] = v;
  }
  // row max: in-lane tree + cross-half
  float t[8];
#pragma unroll
  for (int i = 0; i < 8; ++i) t[i] = fmaxf(p[i], p[i + 8]);
#pragma unroll
  for (int i = 0; i < 4; ++i) t[i] = fmaxf(t[i], t[i + 4]);
  float mx = fmaxf(fmaxf(t[0], t[1]), fmaxf(t[2], t[3]));
  mx = fmaxf(mx, __shfl_xor(mx, 32));
  const float mn = fmaxf(m, mx);
  const float al = exp2f(m - mn);
  m = mn;
#pragma unroll
  for (int r = 0; r < 16; ++r) p[r] = exp2f(p[r] - mn);
  // row sum: in-lane tree + cross-half
  float st[8];
#pragma unroll
  for (int i = 0; i < 8; ++i) st[i] = p[i] + p[i + 8];
#pragma unroll
  for (int i = 0; i < 4; ++i) st[i] = st[i] + st[i + 4];
  float rs = (st[0] + st[1]) + (st[2] + st[3]);
  rs += __shfl_xor(rs, 32);
  lsum = lsum * al + rs;
  o0 *= al;
  o1 *= al;

  // P^T fragments: pack to bf16 pairs, exchange halves with partner lane (l^32)
  u32 w[8], xw[8];
#pragma unroll
  for (int i = 0; i < 8; ++i) w[i] = cvt_pk_bf16(p[2 * i], p[2 * i + 1]);
#pragma unroll
  for (int i = 0; i < 8; ++i) xw[i] = __shfl_xor((int)w[i], 32);
  const u32x4 b0 = hi ? u32x4{xw[2], xw[3], w[2], w[3]} : u32x4{w[0], w[1], xw[0], xw[1]};
  const u32x4 b1 = hi ? u32x4{xw[6], xw[7], w[6], w[7]} : u32x4{w[4], w[5], xw[4], xw[5]};
  const bf16x8 pb0 = __builtin_bit_cast(bf16x8, b0);
  const bf16x8 pb1 = __builtin_bit_cast(bf16x8, b1);

  const u16* vrow = VT + (size_t)(h * DH + ll) * S_LEN + kb + hi * 8;
  o0 = __builtin_amdgcn_mfma_f32_32x32x16_bf16(*(const bf16x8*)&vrow[0],  pb0, o0, 0, 0, 0);
  o0 = __builtin_amdgcn_mfma_f32_32x32x16_bf16(*(const bf16x8*)&vrow[16], pb1, o0, 0, 0, 0);
  const u16* vrow1 = vrow + (size_t)32 * S_LEN;
  o1 = __builtin_amdgcn_mfma_f32_32x32x16_bf16(*(const bf16x8*)&vrow1[0],  pb0, o1, 0, 0, 0);
  o1 = __builtin_amdgcn_mfma_f32_32x32x16_bf16(*(const bf16x8*)&vrow1[16], pb1, o1, 0, 0, 0);
}

__device__ __forceinline__ void attn_strip(const u16* __restrict__ Q, const u16* __restrict__ K,
                                           const u16* __restrict__ VT, u16* __restrict__ O,
                                           int h, int wqb, int ll, int hi, int lld) {
  const u16* qrow = Q + (size_t)(wqb + ll) * DM + h * DH + hi * 8;
  bf16x8 qf[4];
#pragma unroll
  for (int d = 0; d < 4; ++d) qf[d] = *(const bf16x8*)&qrow[d * 16];
  f32x16 o0 = zero16(), o1 = zero16();
  float m = -1e30f, lsum = 0.f;
  const int nt = wqb >> 5;
  for (int kt = 0; kt < nt; ++kt)
    attn_tile<false>(kt << 5, h, ll, hi, lld, K, VT, qf, o0, o1, m, lsum);
  attn_tile<true>(wqb, h, ll, hi, lld, K, VT, qf, o0, o1, m, lsum);

  const float inv = 1.f / lsum;
  u16* orow = O + (size_t)(wqb + ll) * DM + h * DH;
#pragma unroll
  for (int g = 0; g < 4; ++g) {
    ushort4 a;
    a.x = f2bf(o0[g * 4 + 0] * inv); a.y = f2bf(o0[g * 4 + 1] * inv);
    a.z = f2bf(o0[g * 4 + 2] * inv); a.w = f2bf(o0[g * 4 + 3] * inv);
    *(ushort4*)&orow[g * 8 + hi * 4] = a;
    ushort4 b;
    b.x = f2bf(o1[g * 4 + 0] * inv); b.y = f2bf(o1[g * 4 + 1] * inv);
    b.z = f2bf(o1[g * 4 + 2] * inv); b.w = f2bf(o1[g * 4 + 3] * inv);
    *(ushort4*)&orow[32 + g * 8 + hi * 4] = b;
  }
}

// One wave = two complementary 32-row strips (s and 127-s): every wave does
// exactly 129 KV-tiles -> perfect static load balance under the causal mask.
__global__ __launch_bounds__(256) void attn_fwd2(const u16* __restrict__ Q,
                                                 const u16* __restrict__ K,
                                                 const u16* __restrict__ VT,
                                                 u16* __restrict__ O) {
  const int lane = threadIdx.x & 63;
  const int wid = threadIdx.x >> 6;
  const int ll = lane & 31, hi = lane >> 5;
  const int lld = ll - 4 * hi;
  const int h = blockIdx.y;
  const int pr = blockIdx.x * 4 + wid;          // 0..63
  attn_strip(Q, K, VT, O, h, pr * 32, ll, hi, lld);
  attn_strip(Q, K, VT, O, h, (127 - pr) * 32, ll, hi, lld);
}

// ---------------- host launch ----------------
extern "C" void kernel_launch(void* const* d_in, const int* in_sizes, int n_in,
                              void* d_out, int out_size, void* d_ws, size_t ws_size,
                              hipStream_t stream) {
  const float* x  = (const float*)d_in[0];
  const float* Wq = (const float*)d_in[1];
  const float* bq = (const float*)d_in[2];
  const float* Wk = (const float*)d_in[3];
  const float* bk = (const float*)d_in[4];
  const float* Wv = (const float*)d_in[5];
  const float* bv = (const float*)d_in[6];
  const float* Wo = (const float*)d_in[7];
  const float* bo = (const float*)d_in[8];
  float* out = (float*)d_out;

  u16* xb  = (u16*)d_ws;                      // [4096][1024]
  u16* wqb = xb  + (size_t)S_LEN * DM;        // [1024][1024] each
  u16* wkb = wqb + (size_t)DM * DM;
  u16* wvb = wkb + (size_t)DM * DM;
  u16* wob = wvb + (size_t)DM * DM;
  u16* qbf = wob + (size_t)DM * DM;           // [4096][1024]
  u16* kbf = qbf + (size_t)S_LEN * DM;        // [4096][1024]
  u16* vtb = kbf + (size_t)S_LEN * DM;        // [1024][4096]  (V^T)
  u16* obf = vtb + (size_t)S_LEN * DM;        // [4096][1024]

  cvt_bf16<<<(S_LEN * DM / 4 + 255) / 256, 256, 0, stream>>>(x,  xb,  S_LEN * DM / 4);
  cvt_bf16<<<(DM * DM / 4 + 255) / 256, 256, 0, stream>>>(Wq, wqb, DM * DM / 4);
  cvt_bf16<<<(DM * DM / 4 + 255) / 256, 256, 0, stream>>>(Wk, wkb, DM * DM / 4);
  cvt_bf16<<<(DM * DM / 4 + 255) / 256, 256, 0, stream>>>(Wv, wvb, DM * DM / 4);
  cvt_bf16<<<(DM * DM / 4 + 255) / 256, 256, 0, stream>>>(Wo, wob, DM * DM / 4);

  dim3 gg(S_LEN / 128, DM / 128);
  gemm128<0><<<gg, 256, 0, stream>>>(xb, wqb, bq, qbf, S_LEN, DM, DM);
  gemm128<0><<<gg, 256, 0, stream>>>(xb, wkb, bk, kbf, S_LEN, DM, DM);
  gemm128<1><<<gg, 256, 0, stream>>>(xb, wvb, bv, vtb, S_LEN, DM, DM);

  attn_fwd2<<<dim3(16, NH), 256, 0, stream>>>(qbf, kbf, vtb, obf);

  gemm128<2><<<gg, 256, 0, stream>>>(obf, wob, bo, out, S_LEN, DM, DM);
}